// Round 2
// baseline (333.323 us; speedup 1.0000x reference)
//
#include <hip/hip_runtime.h>
#include <math.h>

#define BB 4
#define NN 4096
#define DD 256
#define ROWS (BB * NN)
#define RPB 8   // rows per fill block
#define OUT_BYTES ((size_t)ROWS * NN * 4)   // 268.4 MB
#define DIAG_OFF ((size_t)1 << 20)          // diagnostic region starts 1 MB into ws

typedef float nfloat4 __attribute__((ext_vector_type(4)));  // native vec for nontemporal builtin

// K1: one wave per row. s = dot(h[row,:], w); e[row] = exp(s) (unnormalized —
// max-subtraction cancels exactly in softmax and s~N(0,1) so exp is fp32-safe).
__global__ __launch_bounds__(1024) void k_dot_exp(const float* __restrict__ h,
                                                  const float* __restrict__ w,
                                                  float* __restrict__ e,
                                                  float* __restrict__ partials) {
    const int wid  = threadIdx.x >> 6;          // 0..15
    const int lane = threadIdx.x & 63;
    const int row  = blockIdx.x * 16 + wid;
    __shared__ float lds[16];

    const float4 hv = ((const float4*)(h + (size_t)row * DD))[lane];
    const float4 wv = ((const float4*)w)[lane];
    float acc = hv.x * wv.x + hv.y * wv.y + hv.z * wv.z + hv.w * wv.w;
    #pragma unroll
    for (int off = 32; off; off >>= 1)
        acc += __shfl_down(acc, off, 64);
    if (lane == 0) {
        float ev = __expf(acc);
        e[row] = ev;
        lds[wid] = ev;
    }
    __syncthreads();
    if (threadIdx.x == 0) {
        float s = 0.0f;
        #pragma unroll
        for (int i = 0; i < 16; i++) s += lds[i];
        partials[blockIdx.x] = s;
    }
}

// K2: 4 blocks (one per batch) x 256 threads: reduce 256 partials -> inv_sum[b].
__global__ void k_inv(const float* __restrict__ partials, float* __restrict__ inv) {
    const int b = blockIdx.x;
    const int t = threadIdx.x;
    const int lane = t & 63, wid = t >> 6;
    __shared__ float lds[4];
    float v = partials[b * 256 + t];
    #pragma unroll
    for (int off = 32; off; off >>= 1)
        v += __shfl_down(v, off, 64);
    if (lane == 0) lds[wid] = v;
    __syncthreads();
    if (t == 0)
        inv[b] = 1.0f / (lds[0] + lds[1] + lds[2] + lds[3]);
}

// K3: ALL rows in ONE dispatch (2048 blocks x 8 rows) so its duration rises
// above the ~172 us reset memsets and its counters appear in the top-5.
__global__ __launch_bounds__(256) void k_fill_out(const float* __restrict__ e,
                                                  const float* __restrict__ inv,
                                                  nfloat4* __restrict__ out) {
    const int rb = blockIdx.x * RPB;
    const float ib = inv[rb >> 12];
    const int t = threadIdx.x;
    #pragma unroll
    for (int r = 0; r < RPB; r++) {
        const float v = e[rb + r] * ib;
        const nfloat4 vv = {v, v, v, v};
        nfloat4* o = out + (size_t)(rb + r) * (NN / 4);
        #pragma unroll
        for (int k = 0; k < 4; k++)
            __builtin_nontemporal_store(vv, o + t + k * 256);
    }
}

// DIAGNOSTIC: identical store structure, identical volume (268 MB), identical
// nt path — but targeting d_ws instead of d_out. Discriminates "d_out buffer
// property" (this runs ~45 us @ 6 TB/s) from "footprint/L3 or generic store
// limit" (this runs ~235 us @ 1.1 TB/s). Total dur_us arithmetic tells us
// which, even if this dispatch stays below the top-5 cut.
__global__ __launch_bounds__(256) void k_fill_ws(nfloat4* __restrict__ ws) {
    const int rb = blockIdx.x * RPB;
    const nfloat4 vv = {1.0f, 1.0f, 1.0f, 1.0f};
    const int t = threadIdx.x;
    #pragma unroll
    for (int r = 0; r < RPB; r++) {
        nfloat4* o = ws + (size_t)(rb + r) * (NN / 4);
        #pragma unroll
        for (int k = 0; k < 4; k++)
            __builtin_nontemporal_store(vv, o + t + k * 256);
    }
}

extern "C" void kernel_launch(void* const* d_in, const int* in_sizes, int n_in,
                              void* d_out, int out_size, void* d_ws, size_t ws_size,
                              hipStream_t stream) {
    const float* h = (const float*)d_in[0];
    const float* w = (const float*)d_in[1];
    // d_in[2] (bias) cancels under softmax over axis=1 — unused.
    float* out = (float*)d_out;
    float* e        = (float*)d_ws;         // ROWS floats
    float* partials = e + ROWS;             // ROWS/16 floats
    float* inv      = partials + ROWS / 16; // BB floats  (total < 70 KB at ws base)

    k_dot_exp<<<ROWS / 16, 1024, 0, stream>>>(h, w, e, partials);
    k_inv<<<BB, 256, 0, stream>>>(partials, inv);
    k_fill_out<<<ROWS / RPB, 256, 0, stream>>>(e, inv, (nfloat4*)out);

    // Diagnostic write of 268 MB into ws (region [1MB, 1MB+268MB), far above
    // our live 70 KB scratch). Host-side size guard only — no device sync.
    if (ws_size >= DIAG_OFF + OUT_BYTES) {
        nfloat4* wsdiag = (nfloat4*)((char*)d_ws + DIAG_OFF);
        k_fill_ws<<<ROWS / RPB, 256, 0, stream>>>(wsdiag);
    }
}

// Round 4
// 279.528 us; speedup vs baseline: 1.1924x; 1.1924x over previous
//
#include <hip/hip_runtime.h>
#include <math.h>

#define BB 4
#define NN 4096
#define DD 256
#define ROWS (BB * NN)
#define RPB 8   // rows per fill block

// K1: one wave per row. s = dot(h[row,:], w); e[row] = exp(s) (unnormalized —
// max-subtraction cancels exactly in softmax and s~N(0,1) so exp is fp32-safe).
__global__ __launch_bounds__(1024) void k_dot_exp(const float* __restrict__ h,
                                                  const float* __restrict__ w,
                                                  float* __restrict__ e,
                                                  float* __restrict__ partials) {
    const int wid  = threadIdx.x >> 6;          // 0..15
    const int lane = threadIdx.x & 63;
    const int row  = blockIdx.x * 16 + wid;
    __shared__ float lds[16];

    const float4 hv = ((const float4*)(h + (size_t)row * DD))[lane];
    const float4 wv = ((const float4*)w)[lane];
    float acc = hv.x * wv.x + hv.y * wv.y + hv.z * wv.z + hv.w * wv.w;
    #pragma unroll
    for (int off = 32; off; off >>= 1)
        acc += __shfl_down(acc, off, 64);
    if (lane == 0) {
        float ev = __expf(acc);
        e[row] = ev;
        lds[wid] = ev;
    }
    __syncthreads();
    if (threadIdx.x == 0) {
        float s = 0.0f;
        #pragma unroll
        for (int i = 0; i < 16; i++) s += lds[i];
        partials[blockIdx.x] = s;
    }
}

// K2: 4 blocks (one per batch) x 256 threads: reduce 256 partials -> inv_sum[b].
__global__ void k_inv(const float* __restrict__ partials, float* __restrict__ inv) {
    const int b = blockIdx.x;
    const int t = threadIdx.x;
    const int lane = t & 63, wid = t >> 6;
    __shared__ float lds[4];
    float v = partials[b * 256 + t];
    #pragma unroll
    for (int off = 32; off; off >>= 1)
        v += __shfl_down(v, off, 64);
    if (lane == 0) lds[wid] = v;
    __syncthreads();
    if (t == 0)
        inv[b] = 1.0f / (lds[0] + lds[1] + lds[2] + lds[3]);
}

// K3: single-variable A/B vs round 2: EXACT same structure (2048 blocks x
// 8 rows, 256 threads = full 32-wave/CU residency, 32 stores/thread), but
// PLAIN float4 stores instead of __builtin_nontemporal_store. Round 2
// measured the nt version at ~163 us (~1.65 TB/s); rocclr's plain-store
// memset hits 6.4 TB/s on the same buffers. If the nt flag is the villain,
// this runs ~45 us.
__global__ __launch_bounds__(256) void k_fill_out(const float* __restrict__ e,
                                                  const float* __restrict__ inv,
                                                  float4* __restrict__ out) {
    const int rb = blockIdx.x * RPB;
    const float ib = inv[rb >> 12];
    const int t = threadIdx.x;
    #pragma unroll
    for (int r = 0; r < RPB; r++) {
        const float v = e[rb + r] * ib;
        const float4 vv = {v, v, v, v};
        float4* o = out + (size_t)(rb + r) * (NN / 4);
        #pragma unroll
        for (int k = 0; k < 4; k++)
            o[t + k * 256] = vv;
    }
}

extern "C" void kernel_launch(void* const* d_in, const int* in_sizes, int n_in,
                              void* d_out, int out_size, void* d_ws, size_t ws_size,
                              hipStream_t stream) {
    const float* h = (const float*)d_in[0];
    const float* w = (const float*)d_in[1];
    // d_in[2] (bias) cancels under softmax over axis=1 — unused.
    float* out = (float*)d_out;
    float* e        = (float*)d_ws;         // ROWS floats
    float* partials = e + ROWS;             // ROWS/16 floats
    float* inv      = partials + ROWS / 16; // BB floats

    k_dot_exp<<<ROWS / 16, 1024, 0, stream>>>(h, w, e, partials);
    k_inv<<<BB, 256, 0, stream>>>(partials, inv);
    k_fill_out<<<ROWS / RPB, 256, 0, stream>>>(e, inv, (float4*)out);
}